// Round 2
// baseline (250.395 us; speedup 1.0000x reference)
//
#include <hip/hip_runtime.h>
#include <stdint.h>

#define COLS 4096
#define NEGV (-1000.0f)

// monotone float->uint key: a > b  <=>  key(a) > key(b)   (no NaNs in input)
__device__ __forceinline__ uint32_t f2key(float f) {
    uint32_t u = __float_as_uint(f);
    return u ^ (uint32_t)(((int32_t)u >> 31) | (int32_t)0x80000000);
}

extern "C" __global__ __launch_bounds__(256, 4)
void intent_dropout_kernel(const float* __restrict__ x,
                           const int* __restrict__ pp,
                           float* __restrict__ out) {
    __shared__ uint32_t s_keys[COLS];     // candidate keys (worst case all)
    __shared__ float    s_grpmax[64];
    __shared__ float    s_C;
    __shared__ uint32_t s_cnt;
    __shared__ uint32_t s_Tkey;
    __shared__ uint32_t s_keq;
    __shared__ uint32_t s_eqcnt;
    __shared__ int      s_eqidx[256];

    const int row  = blockIdx.x;
    const int t    = threadIdx.x;
    const int lane = t & 63;
    const uint32_t P = (uint32_t)pp[0];   // == 64; algorithm valid for P <= 64

    const float4* xr = (const float4*)(x + (size_t)row * COLS);
    float4*       orow = (float4*)(out + (size_t)row * COLS);

    // ---- load 16 elements (4 x float4), coalesced ----
    float4 v[4];
#pragma unroll
    for (int j = 0; j < 4; ++j) v[j] = xr[t + 256 * j];

    if (t == 0) { s_cnt = 0u; s_eqcnt = 0u; }

    // ---- C = min over 64 groups (of 64 elems) of group max ------------
    // group(t,j) = 4*(t>>6) + ((t&63)>>4) + 16*j  -> bijection onto 0..63
    // guarantees count(x >= C) >= 64
#pragma unroll
    for (int j = 0; j < 4; ++j) {
        float m = fmaxf(fmaxf(v[j].x, v[j].y), fmaxf(v[j].z, v[j].w));
#pragma unroll
        for (int d = 1; d < 16; d <<= 1) m = fmaxf(m, __shfl_xor(m, d, 64));
        if ((lane & 15) == 0) s_grpmax[(t >> 4) + 16 * j] = m;
    }
    __syncthreads();
    if (t < 64) {
        float g = s_grpmax[t];
#pragma unroll
        for (int d = 1; d < 64; d <<= 1) g = fminf(g, __shfl_xor(g, d, 64));
        if (t == 0) s_C = g;
    }
    __syncthreads();
    const uint32_t Ckey = f2key(s_C);

    // ---- ballot-compact candidate keys into LDS (1 atomic / wave / slot) ----
#define PUSH(F) do {                                                         \
        uint32_t k_ = f2key(F);                                              \
        bool pred_ = (k_ >= Ckey);                                           \
        unsigned long long m_ = __ballot(pred_);                             \
        if (m_) {                                                            \
            int ldr_ = (int)__builtin_ctzll(m_);                             \
            uint32_t base_ = 0u;                                             \
            if (lane == ldr_) base_ = atomicAdd(&s_cnt, (uint32_t)__popcll(m_)); \
            base_ = (uint32_t)__shfl((int)base_, ldr_, 64);                  \
            if (pred_) {                                                     \
                uint32_t off_ = (uint32_t)__popcll(m_ & ((1ull << lane) - 1ull)); \
                s_keys[base_ + off_] = k_;                                   \
            }                                                                \
        }                                                                    \
    } while (0)

#pragma unroll
    for (int j = 0; j < 4; ++j) {
        PUSH(v[j].x); PUSH(v[j].y); PUSH(v[j].z); PUSH(v[j].w);
    }
    __syncthreads();
    const uint32_t M = s_cnt;   // >= 64 guaranteed

    // ---- wave 0: exact MSB radix-select for rank-P key (descending) ----
    if (t < 64) {
        uint32_t rem = P, prefix = 0u;
        if (M <= 1024u) {
            uint32_t kk[16];
#pragma unroll
            for (int q = 0; q < 16; ++q) {
                uint32_t slot = (uint32_t)lane + 64u * q;
                kk[q] = (slot < M) ? s_keys[slot] : 0u;   // pad key 0 never matches
            }
#pragma unroll
            for (int b = 31; b >= 0; --b) {
                uint32_t cand = prefix | (1u << b);
                uint32_t cnt = 0u;
#pragma unroll
                for (int q = 0; q < 16; ++q)
                    cnt += (uint32_t)(((kk[q] ^ cand) >> b) == 0u);
#pragma unroll
                for (int d = 1; d < 64; d <<= 1) cnt += __shfl_xor(cnt, d, 64);
                if (cnt >= rem) prefix = cand; else rem -= cnt;
            }
        } else {  // pathological tie-heavy rows: scan LDS directly
            uint32_t nk = (M + 63u) >> 6;
            for (int b = 31; b >= 0; --b) {
                uint32_t cand = prefix | (1u << b);
                uint32_t cnt = 0u;
                for (uint32_t q = 0; q < nk; ++q) {
                    uint32_t slot = (uint32_t)lane + 64u * q;
                    if (slot < M)
                        cnt += (uint32_t)(((s_keys[slot] ^ cand) >> b) == 0u);
                }
#pragma unroll
                for (int d = 1; d < 64; d <<= 1) cnt += __shfl_xor(cnt, d, 64);
                if (cnt >= rem) prefix = cand; else rem -= cnt;
            }
        }
        if (t == 0) { s_Tkey = prefix; s_keq = rem; }
    }
    __syncthreads();
    const uint32_t Tkey = s_Tkey;
    const uint32_t keq  = s_keq;    // drop first keq elements equal to Tkey (by index)

    // ---- collect indices of elements equal to threshold (normally 1) ----
#define EQPUSH(F, IDX) do {                                                  \
        if (f2key(F) == Tkey) {                                              \
            uint32_t s_ = atomicAdd(&s_eqcnt, 1u);                           \
            if (s_ < 256u) s_eqidx[s_] = (IDX);                              \
        }                                                                    \
    } while (0)

#pragma unroll
    for (int j = 0; j < 4; ++j) {
        EQPUSH(v[j].x, 4 * t + 1024 * j + 0);
        EQPUSH(v[j].y, 4 * t + 1024 * j + 1);
        EQPUSH(v[j].z, 4 * t + 1024 * j + 2);
        EQPUSH(v[j].w, 4 * t + 1024 * j + 3);
    }
    __syncthreads();
    const uint32_t eqc = s_eqcnt;

    // ---- write masked output, coalesced float4 ----
#define PROC(F, IDX) do {                                                    \
        uint32_t k_ = f2key(F);                                              \
        if (k_ > Tkey) { F = NEGV; }                                         \
        else if (k_ == Tkey) {                                               \
            int myi_ = (IDX);                                                \
            uint32_t r_ = 0u;                                                \
            uint32_t n_ = (eqc < 256u) ? eqc : 256u;                         \
            for (uint32_t e = 0; e < n_; ++e)                                \
                r_ += (uint32_t)(s_eqidx[e] < myi_);                         \
            if (r_ < keq) F = NEGV;                                          \
        }                                                                    \
    } while (0)

#pragma unroll
    for (int j = 0; j < 4; ++j) {
        float4 o = v[j];
        PROC(o.x, 4 * t + 1024 * j + 0);
        PROC(o.y, 4 * t + 1024 * j + 1);
        PROC(o.z, 4 * t + 1024 * j + 2);
        PROC(o.w, 4 * t + 1024 * j + 3);
        orow[t + 256 * j] = o;
    }
}

extern "C" void kernel_launch(void* const* d_in, const int* in_sizes, int n_in,
                              void* d_out, int out_size, void* d_ws, size_t ws_size,
                              hipStream_t stream) {
    const float* x  = (const float*)d_in[0];
    const int*   pp = (const int*)d_in[1];   // p == 64
    float*       out = (float*)d_out;
    int rows = in_sizes[0] / COLS;           // 8192
    hipLaunchKernelGGL(intent_dropout_kernel, dim3(rows), dim3(256), 0, stream,
                       x, pp, out);
}

// Round 4
// 231.032 us; speedup vs baseline: 1.0838x; 1.0838x over previous
//
#include <hip/hip_runtime.h>
#include <stdint.h>

#define COLS 4096
#define NEGV (-1000.0f)

// monotone float->uint key: a > b  <=>  key(a) > key(b)   (no NaNs in input)
__device__ __forceinline__ uint32_t f2key(float f) {
    uint32_t u = __float_as_uint(f);
    return u ^ (uint32_t)(((int32_t)u >> 31) | (int32_t)0x80000000);
}
// exact bitwise inverse of f2key
__device__ __forceinline__ float key2f(uint32_t k) {
    uint32_t u = (k & 0x80000000u) ? (k ^ 0x80000000u) : ~k;
    return __uint_as_float(u);
}

// Block-parallel "find the bin containing the rem-th largest" over a histogram.
// Thread t owns PER consecutive bins [t*PER, (t+1)*PER). Higher bin = larger key.
// Writes (bin, rem_within_bin) to s_dig/s_rem; contains 2 __syncthreads.
template <int PER>
__device__ __forceinline__ void find_bin(const uint32_t* hist, int t, int lane, int wave,
                                         uint32_t rem, uint32_t* s_wsum,
                                         volatile uint32_t* s_dig, volatile uint32_t* s_rem) {
    const int base = t * PER;
    uint32_t own[PER];
    uint32_t L = 0;
#pragma unroll
    for (int i = 0; i < PER; ++i) { own[i] = hist[base + i]; L += own[i]; }
    // inclusive suffix-sum within wave (lane gets sum over lanes >= lane)
    uint32_t inc = L;
#pragma unroll
    for (int d = 1; d < 64; d <<= 1) {
        uint32_t tmp = (uint32_t)__shfl_down((int)inc, d, 64);
        if (lane + d < 64) inc += tmp;
    }
    if (lane == 0) s_wsum[wave] = inc;     // wave total
    __syncthreads();
    uint32_t U = inc - L;                  // exclusive suffix within wave
#pragma unroll
    for (int w = 1; w < 4; ++w) if (wave + w < 4) U += s_wsum[wave + w];
    // walk own bins from the top; exactly one (t,i) satisfies the crossing
    uint32_t acc = U;                      // count of candidates in bins > current
#pragma unroll
    for (int i = PER - 1; i >= 0; --i) {
        uint32_t h = own[i];
        if (h != 0u && acc < rem && rem <= acc + h) {
            *s_dig = (uint32_t)(base + i);
            *s_rem = rem - acc;
        }
        acc += h;
    }
    __syncthreads();
}

extern "C" __global__ __launch_bounds__(256, 8)
void intent_dropout_kernel(const float* __restrict__ x,
                           const int* __restrict__ pp,
                           float* __restrict__ out) {
    __shared__ uint32_t s_h1[2048];     // level-1 hist; low 1024 reused for level 3
    __shared__ uint32_t s_h2[2048];     // level-2 hist; reused as tie-index list
    __shared__ uint32_t s_grpmax[64];
    __shared__ uint32_t s_wsum[4];
    __shared__ uint32_t s_Ckey;
    __shared__ uint32_t s_dig, s_remv;
    __shared__ uint32_t s_eqcnt;

    const int row  = blockIdx.x;
    const int t    = threadIdx.x;
    const int lane = t & 63;
    const int wave = t >> 6;
    const uint32_t P = (uint32_t)pp[0];      // == 64 (valid for P <= 64)

    const float4* xr   = (const float4*)(x + (size_t)row * COLS);
    float4*       orow = (float4*)(out + (size_t)row * COLS);

    // ---- phase 0: load -> keys (floats not kept; key2f reconstructs), zero hists ----
    uint32_t keys[16];
#pragma unroll
    for (int j = 0; j < 4; ++j) {
        float4 v = xr[t + 256 * j];
        keys[4 * j + 0] = f2key(v.x);
        keys[4 * j + 1] = f2key(v.y);
        keys[4 * j + 2] = f2key(v.z);
        keys[4 * j + 3] = f2key(v.w);
    }
#pragma unroll
    for (int i = 0; i < 8; ++i) { s_h1[t + 256 * i] = 0u; s_h2[t + 256 * i] = 0u; }
    if (t == 0) s_eqcnt = 0u;

    // C = min over 64 disjoint groups (64 elems each) of group max  =>  >= 64 cands >= C
#pragma unroll
    for (int j = 0; j < 4; ++j) {
        uint32_t m = max(max(keys[4 * j], keys[4 * j + 1]), max(keys[4 * j + 2], keys[4 * j + 3]));
#pragma unroll
        for (int d = 1; d < 16; d <<= 1) m = max(m, (uint32_t)__shfl_xor((int)m, d, 64));
        if ((lane & 15) == 0) s_grpmax[(t >> 4) + 16 * j] = m;
    }
    __syncthreads();

    if (t < 64) {
        uint32_t g = s_grpmax[t];
#pragma unroll
        for (int d = 1; d < 64; d <<= 1) g = min(g, (uint32_t)__shfl_xor((int)g, d, 64));
        if (t == 0) s_Ckey = g;
    }
    __syncthreads();
    const uint32_t Ckey = s_Ckey;

    // ---- level 1: hist of candidate keys on bits [31:21] ----
#pragma unroll
    for (int i = 0; i < 16; ++i)
        if (keys[i] >= Ckey) atomicAdd(&s_h1[keys[i] >> 21], 1u);
    __syncthreads();
    find_bin<8>(s_h1, t, lane, wave, P, s_wsum, &s_dig, &s_remv);
    const uint32_t d1   = s_dig;
    const uint32_t rem1 = s_remv;

    // ---- level 2: bits [20:10] within bin d1; re-zero h1 low 1024 for level 3 ----
#pragma unroll
    for (int i = 0; i < 4; ++i) s_h1[t + 256 * i] = 0u;
#pragma unroll
    for (int i = 0; i < 16; ++i)
        if (keys[i] >= Ckey && (keys[i] >> 21) == d1)
            atomicAdd(&s_h2[(keys[i] >> 10) & 0x7FFu], 1u);
    __syncthreads();
    find_bin<8>(s_h2, t, lane, wave, rem1, s_wsum, &s_dig, &s_remv);
    const uint32_t d2   = s_dig;
    const uint32_t rem2 = s_remv;
    const uint32_t pre21 = (d1 << 11) | d2;

    // ---- level 3: bits [9:0] within (d1,d2) ----
#pragma unroll
    for (int i = 0; i < 16; ++i)
        if (keys[i] >= Ckey && (keys[i] >> 10) == pre21)
            atomicAdd(&s_h1[keys[i] & 0x3FFu], 1u);
    __syncthreads();
    find_bin<4>(s_h1, t, lane, wave, rem2, s_wsum, &s_dig, &s_remv);
    const uint32_t Tkey = (pre21 << 10) | s_dig;   // exact rank-P key
    const uint32_t keq  = s_remv;                  // #ties at Tkey to drop (smallest idx first)

    // ---- collect indices equal to threshold (normally 1); list lives in s_h2 ----
#pragma unroll
    for (int j = 0; j < 4; ++j) {
#pragma unroll
        for (int c = 0; c < 4; ++c) {
            if (keys[4 * j + c] == Tkey) {
                uint32_t s = atomicAdd(&s_eqcnt, 1u);
                if (s < 2048u) s_h2[s] = (uint32_t)(4 * t + 1024 * j + c);
            }
        }
    }
    __syncthreads();
    const uint32_t eqc = (s_eqcnt < 2048u) ? s_eqcnt : 2048u;

    // ---- masked write, coalesced float4 (floats reconstructed from keys) ----
#pragma unroll
    for (int j = 0; j < 4; ++j) {
        float4 o;
        float* comp = (float*)&o;
#pragma unroll
        for (int c = 0; c < 4; ++c) {
            uint32_t k = keys[4 * j + c];
            float f;
            if (k > Tkey) {
                f = NEGV;
            } else if (k == Tkey) {
                uint32_t myi = (uint32_t)(4 * t + 1024 * j + c);
                uint32_t r = 0;
                for (uint32_t e = 0; e < eqc; ++e) r += (uint32_t)(s_h2[e] < myi);
                f = (r < keq) ? NEGV : key2f(k);
            } else {
                f = key2f(k);
            }
            comp[c] = f;
        }
        orow[t + 256 * j] = o;
    }
}

extern "C" void kernel_launch(void* const* d_in, const int* in_sizes, int n_in,
                              void* d_out, int out_size, void* d_ws, size_t ws_size,
                              hipStream_t stream) {
    const float* x   = (const float*)d_in[0];
    const int*   pp  = (const int*)d_in[1];
    float*       out = (float*)d_out;
    int rows = in_sizes[0] / COLS;           // 8192
    hipLaunchKernelGGL(intent_dropout_kernel, dim3(rows), dim3(256), 0, stream,
                       x, pp, out);
}